// Round 8
// baseline (604.694 us; speedup 1.0000x reference)
//
#include <hip/hip_runtime.h>
#include <hip/hip_bf16.h>

#define DIN 256
#define DOUT 128

using short8  = __attribute__((ext_vector_type(8))) short;
using floatx4 = __attribute__((ext_vector_type(4))) float;

__device__ __forceinline__ unsigned short f2bf(float f) {
    union { float f; unsigned u; } x; x.f = f;
    unsigned u = x.u;
    unsigned r = u + 0x7fffu + ((u >> 16) & 1u);   // round-to-nearest-even
    return (unsigned short)(r >> 16);
}

// 2 floats -> packed bf16x2; compiler emits v_cvt_pk_bf16_f32
__device__ __forceinline__ unsigned cvt2(float x, float y) {
    union { __hip_bfloat162 h2; unsigned u; } c;
    c.h2 = __float22bfloat162_rn(float2{x, y});
    return c.u;
}

// Bfrag in MFMA-fragment order, lane-major (verified R2/R4/R5/R7):
//   Bfrag[((ct*8 + ks)*64 + lane)*8 + j] = bf16(W0[(ks*32 + (lane>>4)*8 + j)][ct*16 + (lane&15)])
__global__ void w0_pack_kernel(const float* __restrict__ W0,
                               unsigned short* __restrict__ Bfrag) {
    int e = blockIdx.x * blockDim.x + threadIdx.x;   // 32768 elements
    int j  = e & 7;
    int l  = (e >> 3) & 63;
    int ks = (e >> 9) & 7;
    int ct = e >> 12;
    int k = ks * 32 + (l >> 4) * 8 + j;
    int c = ct * 16 + (l & 15);
    Bfrag[e] = f2bf(W0[k * DOUT + c]);
}

// 512 threads = 8 waves; each wave owns 16 nodes x all 128 cols per tile
// and free-runs over T tiles with NO inter-tile barrier, so waves on a CU
// desynchronize and keep the memory pipe continuously busy.
__global__ __launch_bounds__(512, 4) void fused_embed_kernel(
    const float* __restrict__ feat0,
    const float* __restrict__ emb_table,
    const unsigned short* __restrict__ Bfrag,
    const int* __restrict__ node_ids,
    const int* __restrict__ node_tids,
    const int* __restrict__ type_ids,
    float* __restrict__ out,
    int n, int T)
{
    __shared__ short8 sB[4096];   // [ct][ks][lane] = 64 KB

    const int t    = threadIdx.x;
    const int w    = t >> 6;      // wave 0..7
    const int l    = t & 63;
    const int lr   = l & 15;      // A row in wave tile / D col
    const int kg   = l >> 4;      // k-group / D row group
    const int crow = l >> 2;      // copy path: row 0..15
    const int csub = l & 3;       // copy path: 4 lanes per row

    // ---- idx for this wave's first tile (earliest issue) ----
    const long long wbase = ((long long)blockIdx.x * 8 + w) * ((long long)T * 16);
    int tid = -1, gt = 0, gn = 0;
    {
        const long long row0 = wbase + lr;
        if (row0 < n) { tid = node_tids[row0]; gt = type_ids[row0]; gn = node_ids[row0]; }
    }

    // ---- stage B (reg-staged coalesced copy) ----
    {
        const short8* src = reinterpret_cast<const short8*>(Bfrag);
        short8 tmp[8];
        #pragma unroll
        for (int j = 0; j < 8; ++j) tmp[j] = src[t + j * 512];
        #pragma unroll
        for (int j = 0; j < 8; ++j) sB[t + j * 512] = tmp[j];
    }

    __syncthreads();   // the ONLY barrier; waves free-run afterwards

    for (int tt = 0; tt < T; ++tt) {
        const long long nodebase = wbase + (long long)tt * 16;

        // ---- issue A gathers; featureless lanes hit row 0 (L1 dedup) ----
        const int gts = (tid == 0) ? gt : 0;
        const float4* arow = reinterpret_cast<const float4*>(
            feat0 + (long long)gts * DIN) + kg * 2;
        float4 av[16];
        #pragma unroll
        for (int ks = 0; ks < 8; ++ks) {
            av[2 * ks]     = arow[ks * 8];
            av[2 * ks + 1] = arow[ks * 8 + 1];
        }

        // ---- issue emb-copy loads (4 lanes per row) ----
        const int t_c  = __shfl(tid, crow);
        const int gn_c = __shfl(gn, crow);
        const long long cnode = nodebase + crow;
        const bool copyrow = (t_c == 1) && (cnode < n);
        const int  gns = copyrow ? gn_c : 0;
        const float4* esrc = reinterpret_cast<const float4*>(
            emb_table + (long long)gns * DOUT);
        float4 ev[8];
        #pragma unroll
        for (int j = 0; j < 8; ++j) ev[j] = esrc[csub + j * 4];

        const int tidS = tid;

        // ---- prefetch next tile's idx (lands under cvt+MFMA) ----
        if (tt + 1 < T) {
            const long long rown = nodebase + 16 + lr;
            tid = -1;
            if (rown < n) { tid = node_tids[rown]; gt = type_ids[rown]; gn = node_ids[rown]; }
        }

        // ---- convert (v_cvt_pk_bf16_f32) + MFMA ----
        floatx4 acc[8];
        #pragma unroll
        for (int ct = 0; ct < 8; ++ct) acc[ct] = (floatx4){0.f, 0.f, 0.f, 0.f};
        #pragma unroll
        for (int ks = 0; ks < 8; ++ks) {
            const float4 a0 = av[2 * ks];
            const float4 a1 = av[2 * ks + 1];
            union { short8 s; unsigned u[4]; } af;
            af.u[0] = cvt2(a0.x, a0.y);
            af.u[1] = cvt2(a0.z, a0.w);
            af.u[2] = cvt2(a1.x, a1.y);
            af.u[3] = cvt2(a1.z, a1.w);
            #pragma unroll
            for (int ct = 0; ct < 8; ++ct)
                acc[ct] = __builtin_amdgcn_mfma_f32_16x16x32_bf16(
                    af.s, sB[(ct * 8 + ks) * 64 + l], acc[ct], 0, 0, 0);
        }

        // ---- store projected rows (D: row = kg*4+r, col = ct*16+lr) ----
        #pragma unroll
        for (int r = 0; r < 4; ++r) {
            const int row = kg * 4 + r;
            const int t_r = __shfl(tidS, row);
            const long long node = nodebase + row;
            if (t_r == 0 && node < n) {
                float* orow = out + node * DOUT;
                #pragma unroll
                for (int ct = 0; ct < 8; ++ct)
                    orow[ct * 16 + lr] = acc[ct][r];
            }
        }

        // ---- featureless-row stores (ev landed long ago) ----
        if (copyrow) {
            float4* dst = reinterpret_cast<float4*>(out + cnode * DOUT);
            #pragma unroll
            for (int j = 0; j < 8; ++j) dst[csub + j * 4] = ev[j];
        }
    }
}

extern "C" void kernel_launch(void* const* d_in, const int* in_sizes, int n_in,
                              void* d_out, int out_size, void* d_ws, size_t ws_size,
                              hipStream_t stream) {
    const float* feat0      = (const float*)d_in[0];
    const float* W0         = (const float*)d_in[1];
    const float* emb_table  = (const float*)d_in[2];
    const int*   node_ids   = (const int*)d_in[3];
    const int*   node_tids  = (const int*)d_in[4];
    const int*   type_ids   = (const int*)d_in[5];
    float*       out        = (float*)d_out;
    const int n = in_sizes[3];                      // N = 500000

    unsigned short* Bfrag = (unsigned short*)d_ws;  // 64 KB in workspace

    hipLaunchKernelGGL(w0_pack_kernel, dim3((DIN * DOUT) / 256), dim3(256),
                       0, stream, W0, Bfrag);

    const int T = 4;                                   // tiles per wave
    const int wtiles = (n + 15) / 16;                  // 31250
    const int grid = (wtiles + 8 * T - 1) / (8 * T);   // 977
    hipLaunchKernelGGL(fused_embed_kernel, dim3(grid), dim3(512), 0, stream,
                       feat0, emb_table, Bfrag, node_ids, node_tids, type_ids,
                       out, n, T);
}

// Round 9
// 159.740 us; speedup vs baseline: 3.7855x; 3.7855x over previous
//
#include <hip/hip_runtime.h>
#include <hip/hip_bf16.h>

#define DIN 256
#define DOUT 128
#define ROWS 32            // nodes per tile
#define TPB  16            // tiles per block

using short8  = __attribute__((ext_vector_type(8))) short;
using floatx4 = __attribute__((ext_vector_type(4))) float;

__device__ __forceinline__ unsigned short f2bf(float f) {
    union { float f; unsigned u; } x; x.f = f;
    unsigned u = x.u;
    unsigned r = u + 0x7fffu + ((u >> 16) & 1u);   // round-to-nearest-even
    return (unsigned short)(r >> 16);
}

// 2 floats -> packed bf16x2 (v_cvt_pk_bf16_f32)
__device__ __forceinline__ unsigned cvt2(float x, float y) {
    union { __hip_bfloat162 h2; unsigned u; } c;
    c.h2 = __float22bfloat162_rn(float2{x, y});
    return c.u;
}

// Bfrag in MFMA-fragment order, lane-major (verified R2..R7):
//   Bfrag[((ct*8 + ks)*64 + lane)*8 + j] = bf16(W0[(ks*32 + (lane>>4)*8 + j)][ct*16 + (lane&15)])
__global__ void w0_pack_kernel(const float* __restrict__ W0,
                               unsigned short* __restrict__ Bfrag) {
    int e = blockIdx.x * blockDim.x + threadIdx.x;   // 32768 elements
    int j  = e & 7;
    int l  = (e >> 3) & 63;
    int ks = (e >> 9) & 7;
    int ct = e >> 12;
    int k = ks * 32 + (l >> 4) * 8 + j;
    int c = ct * 16 + (l & 15);
    Bfrag[e] = f2bf(W0[k * DOUT + c]);
}

// 512 threads = 8 waves. Per 32-node tile: feat0 rows DMA'd row-per-instr
// (global_load_lds, 4x256B segments/row, zero VGPR payload) into a
// double-buffered LDS tile with source-chunk XOR swizzle; B fragments in
// registers (wave w owns cols w*16..+15); emb rows copied 16-lane/row.
// One barrier per tile; its vmcnt(0) drain IS the DMA prefetch wait.
__global__ __launch_bounds__(512, 4) void fused_embed_kernel(
    const float* __restrict__ feat0,
    const float* __restrict__ emb_table,
    const unsigned short* __restrict__ Bfrag,
    const int* __restrict__ node_ids,
    const int* __restrict__ node_tids,
    const int* __restrict__ type_ids,
    float* __restrict__ out,
    int n, long long ntiles)
{
    __shared__ float sA[2][ROWS * DIN];   // 2 x 32 KB fp32

    const int t  = threadIdx.x;
    const int w  = t >> 6;        // wave 0..7 = output col tile
    const int l  = t & 63;
    const int lr = l & 15;        // A row in 16-row subtile / D col
    const int kg = l >> 4;        // k-group / D row group

    // ---- B fragments: 32 VGPR/wave, loaded once ----
    short8 bf[8];
    {
        const short8* bsrc = reinterpret_cast<const short8*>(Bfrag);
        #pragma unroll
        for (int ks = 0; ks < 8; ++ks)
            bf[ks] = bsrc[(w * 8 + ks) * 64 + l];
    }

    const long long tile0   = (long long)blockIdx.x * TPB;
    const long long tileEnd = (tile0 + TPB < ntiles) ? tile0 + TPB : ntiles;
    if (tile0 >= tileEnd) return;

    // lanes 0..31 hold row (l&31)'s indices; others duplicate
    auto loadIdx = [&](long long tt, int& tid, int& gt, int& gn) {
        tid = -1; gt = 0; gn = 0;
        const long long node = tt * ROWS + (l & 31);
        if (node < n) { tid = node_tids[node]; gt = type_ids[node]; gn = node_ids[node]; }
    };

    // wave w DMAs rows w*4..w*4+3; source chunk pre-swizzled by (row&7)
    auto issueDMA = [&](int buf, int tidN, int gtN) {
        #pragma unroll
        for (int rj = 0; rj < 4; ++rj) {
            const int row  = w * 4 + rj;
            const int tidr = __shfl(tidN, row);
            const int gtr  = __shfl(gtN, row);
            const int gts  = (tidr == 0) ? gtr : 0;   // featureless -> row 0
            const float* gsrc = feat0 + (long long)gts * DIN
                                + ((l ^ (row & 7)) << 2);   // chunk = lane^(row&7)
            __builtin_amdgcn_global_load_lds(
                (const __attribute__((address_space(1))) unsigned int*)gsrc,
                (__attribute__((address_space(3))) unsigned int*)(&sA[buf][row * DIN]),
                16, 0, 0);
        }
    };

    // ---- prologue ----
    int tidC, gtC, gnC, tidN, gtN, gnN;
    loadIdx(tile0, tidC, gtC, gnC);
    if (tile0 + 1 < tileEnd) loadIdx(tile0 + 1, tidN, gtN, gnN);
    else { tidN = -1; gtN = 0; gnN = 0; }
    issueDMA(0, tidC, gtC);
    __syncthreads();   // drains DMA for tile0

    for (long long tt = tile0; tt < tileEnd; ++tt) {
        const int cur = (int)((tt - tile0) & 1);

        // 1. DMA next tile into the other buffer (in flight this whole iter)
        if (tt + 1 < tileEnd) issueDMA(cur ^ 1, tidN, gtN);

        // 2. emb-copy loads for current tile: wave w rows w*4..+3, 16 lanes/row
        const int crow = w * 4 + (l >> 4);
        const int csub = l & 15;
        const int t_c  = __shfl(tidC, crow);
        const int gn_c = __shfl(gnC, crow);
        const long long cnode = tt * ROWS + crow;
        const bool copyrow = (t_c == 1) && (cnode < n);
        const float4* esrc = reinterpret_cast<const float4*>(
            emb_table + (long long)(copyrow ? gn_c : 0) * DOUT) + csub * 2;
        const float4 e0 = esrc[0];
        const float4 e1 = esrc[1];

        // 3. prefetch idx for tile tt+2
        int tid2, gt2, gn2;
        if (tt + 2 < tileEnd) loadIdx(tt + 2, tid2, gt2, gn2);
        else { tid2 = -1; gt2 = 0; gn2 = 0; }

        // 4. MFMA from sA[cur]; A-read swizzle matches DMA source swizzle
        floatx4 acc[2];
        acc[0] = (floatx4){0.f, 0.f, 0.f, 0.f};
        acc[1] = (floatx4){0.f, 0.f, 0.f, 0.f};
        const char* abase = reinterpret_cast<const char*>(&sA[cur][0]);
        #pragma unroll
        for (int ks = 0; ks < 8; ++ks) {
            #pragma unroll
            for (int rt = 0; rt < 2; ++rt) {
                const int row = rt * 16 + lr;
                const int c0  = ks * 8 + kg * 2;
                const unsigned a0 = (unsigned)(row * 1024) + (unsigned)(((c0)     ^ (row & 7)) << 4);
                const unsigned a1 = (unsigned)(row * 1024) + (unsigned)(((c0 + 1) ^ (row & 7)) << 4);
                const float4 f0 = *reinterpret_cast<const float4*>(abase + a0);
                const float4 f1 = *reinterpret_cast<const float4*>(abase + a1);
                union { short8 s; unsigned u[4]; } af;
                af.u[0] = cvt2(f0.x, f0.y);
                af.u[1] = cvt2(f0.z, f0.w);
                af.u[2] = cvt2(f1.x, f1.y);
                af.u[3] = cvt2(f1.z, f1.w);
                acc[rt] = __builtin_amdgcn_mfma_f32_16x16x32_bf16(
                    af.s, bf[ks], acc[rt], 0, 0, 0);
            }
        }

        // 5. store projected rows (D: row = rt*16 + kg*4 + r, col = w*16 + lr)
        #pragma unroll
        for (int rt = 0; rt < 2; ++rt) {
            #pragma unroll
            for (int r = 0; r < 4; ++r) {
                const int row = rt * 16 + kg * 4 + r;
                const int t_r = __shfl(tidC, row);
                const long long node = tt * ROWS + row;
                if (t_r == 0 && node < n)
                    out[node * DOUT + w * 16 + lr] = acc[rt][r];
            }
        }

        // 6. emb-copy stores
        if (copyrow) {
            float4* dst = reinterpret_cast<float4*>(out + cnode * DOUT) + csub * 2;
            dst[0] = e0; dst[1] = e1;
        }

        // 7. rotate indices; barrier publishes next buffer (drains DMA)
        tidC = tidN; gtC = gtN; gnC = gnN;
        tidN = tid2; gtN = gt2; gnN = gn2;
        __syncthreads();
    }
}

extern "C" void kernel_launch(void* const* d_in, const int* in_sizes, int n_in,
                              void* d_out, int out_size, void* d_ws, size_t ws_size,
                              hipStream_t stream) {
    const float* feat0      = (const float*)d_in[0];
    const float* W0         = (const float*)d_in[1];
    const float* emb_table  = (const float*)d_in[2];
    const int*   node_ids   = (const int*)d_in[3];
    const int*   node_tids  = (const int*)d_in[4];
    const int*   type_ids   = (const int*)d_in[5];
    float*       out        = (float*)d_out;
    const int n = in_sizes[3];                      // N = 500000

    unsigned short* Bfrag = (unsigned short*)d_ws;  // 64 KB in workspace

    hipLaunchKernelGGL(w0_pack_kernel, dim3((DIN * DOUT) / 256), dim3(256),
                       0, stream, W0, Bfrag);

    const long long ntiles = (n + ROWS - 1) / ROWS;          // 15625
    const int grid = (int)((ntiles + TPB - 1) / TPB);        // 977
    hipLaunchKernelGGL(fused_embed_kernel, dim3(grid), dim3(512), 0, stream,
                       feat0, emb_table, Bfrag, node_ids, node_tids, type_ids,
                       out, n, ntiles);
}